// Round 4
// baseline (204.530 us; speedup 1.0000x reference)
//
#include <hip/hip_runtime.h>

typedef unsigned short u16;
typedef __attribute__((ext_vector_type(8))) short bf16x8;
typedef __attribute__((ext_vector_type(4))) float f32x4;

#define BK 64
#define TM 2
#define BM 64

__device__ __forceinline__ u16 f2bf(float f) {
    unsigned u = __float_as_uint(f);
    unsigned r = u + 0x7fffu + ((u >> 16) & 1u);
    return (u16)(r >> 16);
}
__device__ __forceinline__ float bf2f(u16 h) {
    return __uint_as_float(((unsigned)h) << 16);
}

__device__ __forceinline__ void gload_lds16(const u16* g, u16* l) {
    __builtin_amdgcn_global_load_lds(
        (__attribute__((address_space(1))) unsigned int*)(u16*)g,
        (__attribute__((address_space(3))) unsigned int*)l,
        16, 0, 0);
}

// ---------- W transpose + rowsum zeroing (x conversion now fused into QKV) ----
// blocks [0,1728): kernel[3][768][768] fp32 -> Wt[j*768+o][d] bf16 (transpose)
// block 1728: zero rowsum[8192]
__global__ __launch_bounds__(256) void cvt_in_kernel(const float* __restrict__ W,
                                                     u16* __restrict__ Wt,
                                                     float* __restrict__ rsum) {
    const int bid = blockIdx.x;
    const int tid = threadIdx.x;
    if (bid < 1728) {
        __shared__ float t[32][33];
        const int j = bid / 576;
        const int rem = bid - j * 576;
        const int d0 = (rem % 24) * 32, o0 = (rem / 24) * 32;
        const int tx = tid & 31, ty = tid >> 5;
#pragma unroll
        for (int i = 0; i < 4; i++) {
            int d = d0 + ty + i * 8;
            t[ty + i * 8][tx] = W[((long)j * 768 + d) * 768 + o0 + tx];
        }
        __syncthreads();
#pragma unroll
        for (int i = 0; i < 4; i++) {
            int o = o0 + ty + i * 8;
            Wt[((long)j * 768 + o) * 768 + d0 + tx] = f2bf(t[tx][ty + i * 8]);
        }
    } else {
        const float4 z4 = {0.f, 0.f, 0.f, 0.f};
#pragma unroll
        for (int j = 0; j < 8; j++) ((float4*)rsum)[tid * 8 + j] = z4;
    }
}

// 16 MFMA on one staged K-tile (XOR-swizzled LDS layout)
__device__ __forceinline__ void compute_tile(const u16* As, const u16* Bs,
                                             f32x4 (&acc)[TM][4], int wm, int wn,
                                             int q, int rA) {
#pragma unroll
    for (int kk = 0; kk < BK; kk += 32) {
        const int gchunk = (kk >> 3) + q;
        bf16x8 af[TM], bfr[4];
#pragma unroll
        for (int mi = 0; mi < TM; ++mi) {
            const int R = wm + mi * 16 + rA;
            af[mi] = *(const bf16x8*)&As[R * 64 + ((gchunk ^ (R & 7)) << 3)];
        }
#pragma unroll
        for (int ni = 0; ni < 4; ++ni) {
            const int R = wn + ni * 16 + rA;
            bfr[ni] = *(const bf16x8*)&Bs[R * 64 + ((gchunk ^ (R & 7)) << 3)];
        }
#pragma unroll
        for (int mi = 0; mi < TM; ++mi)
#pragma unroll
            for (int ni = 0; ni < 4; ++ni)
                acc[mi][ni] = __builtin_amdgcn_mfma_f32_16x16x32_bf16(
                    af[mi], bfr[ni], acc[mi][ni], 0, 0, 0);
    }
}

// ---------- GEMM: C = A(MxK) * Bt(NxK)^T, bf16 in, fp32 acc ----------
// 64x128 tile, SINGLE-buffer LDS (dbuf was measured null-to-negative here:
// occupancy 37->23, QKV 45.6->48.8), XCD-chunked bijective swizzle (kept:
// QKV FETCH 56.5->40MB).
// MODE 0: QKV from RAW x fp32 (A reg-staged + f32->bf16 cvt; B=Wt gload_lds).
//         by<12 -> Q/K bf16 direct; by>=12 -> V written TRANSPOSED via LDS.
// MODE 1: P~ = exp(s*scale) bf16 + per-row atomic sum into rsum.
// MODE 2: out = acc / rsum[row] -> fp32.
template <int MODE>
__global__ __launch_bounds__(256)
void gemm_bt_kernel(const u16* __restrict__ A, const float* __restrict__ Af,
                    const u16* __restrict__ Bt,
                    u16* __restrict__ o16, float* __restrict__ o32,
                    u16* __restrict__ vt, float* __restrict__ rsum,
                    int K, long sA, long sB, long sO, int ldc, float scale,
                    int ny, int nxy) {
    __shared__ __align__(16) u16 smem[BM * BK + 128 * BK];   // 24576 B
    u16* As = smem;
    u16* Bs = smem + BM * BK;

    // bijective XCD-chunked swizzle: each XCD gets a contiguous task range,
    // by-inner so the B z-slice stays L2-resident per XCD and A panels are
    // reused by consecutive blocks.
    const int nb = gridDim.x;            // divisible by 8
    const int chunk = nb >> 3;
    const int nl = (blockIdx.x & 7) * chunk + (blockIdx.x >> 3);
    const int bz = nl / nxy;
    const int rem = nl - bz * nxy;
    const int bx = rem / ny;
    const int by = rem - bx * ny;

    const int tid = threadIdx.x;
    const int lane = tid & 63;
    const int wave = tid >> 6;

    const u16* Bb = Bt + (long)bz * sB + (long)by * 128 * K;

    const int rl = lane >> 3;   // row within 8-row staging group
    const int pc = lane & 7;    // 16B chunk position within row
    const int q = lane >> 4;    // quad
    const int rA = lane & 15;
    const int wm = (wave >> 1) * (TM * 16);
    const int wn = (wave & 1) * 64;

    f32x4 acc[TM][4];
    const f32x4 zero = {0.f, 0.f, 0.f, 0.f};
#pragma unroll
    for (int i = 0; i < TM; i++)
#pragma unroll
        for (int j = 0; j < 4; j++) acc[i][j] = zero;

    if (MODE == 0) {
        // ---- A reg-staged from fp32 x; B via gload_lds from Wt ----
        const float* Ax = Af + (long)bx * BM * 768;
        const int c = tid & 7;           // 8-u16 chunk within row
        const int r0 = tid >> 3;         // rows r0 and r0+32 ((r0+32)&7 == r0&7)
        const long g0 = (long)r0 * 768 + c * 8;
        const long g1 = (long)(r0 + 32) * 768 + c * 8;
        const int sw = (c ^ (r0 & 7)) << 3;
        // prologue: issue A-loads for k0=0
        float4 a00 = *(const float4*)(Ax + g0);
        float4 a01 = *(const float4*)(Ax + g0 + 4);
        float4 a10 = *(const float4*)(Ax + g1);
        float4 a11 = *(const float4*)(Ax + g1 + 4);
        for (int k0 = 0; k0 < K; k0 += BK) {
            // convert + swizzled store of current A regs
            bf16x8 v0, v1;
            v0[0] = f2bf(a00.x); v0[1] = f2bf(a00.y);
            v0[2] = f2bf(a00.z); v0[3] = f2bf(a00.w);
            v0[4] = f2bf(a01.x); v0[5] = f2bf(a01.y);
            v0[6] = f2bf(a01.z); v0[7] = f2bf(a01.w);
            v1[0] = f2bf(a10.x); v1[1] = f2bf(a10.y);
            v1[2] = f2bf(a10.z); v1[3] = f2bf(a10.w);
            v1[4] = f2bf(a11.x); v1[5] = f2bf(a11.y);
            v1[6] = f2bf(a11.z); v1[7] = f2bf(a11.w);
            *(bf16x8*)&As[r0 * 64 + sw] = v0;
            *(bf16x8*)&As[(r0 + 32) * 64 + sw] = v1;
            // B tile via gload_lds (bf16 already)
#pragma unroll
            for (int t = 0; t < 4; ++t) {
                const int issue = wave + t * 4;
                const int row = issue * 8 + rl;
                const int gc = pc ^ (row & 7);
                gload_lds16(Bb + (long)row * K + k0 + gc * 8, &Bs[issue * 512]);
            }
            __syncthreads();
            // prefetch next A tile into regs (hides under MFMA phase)
            if (k0 + BK < K) {
                a00 = *(const float4*)(Ax + g0 + k0 + BK);
                a01 = *(const float4*)(Ax + g0 + k0 + BK + 4);
                a10 = *(const float4*)(Ax + g1 + k0 + BK);
                a11 = *(const float4*)(Ax + g1 + k0 + BK + 4);
            }
            compute_tile(As, Bs, acc, wm, wn, q, rA);
            __syncthreads();
        }
    } else {
        // ---- both operands bf16 via gload_lds ----
        const u16* Ab = A + (long)bz * sA + (long)bx * BM * K;
        for (int k0 = 0; k0 < K; k0 += BK) {
#pragma unroll
            for (int t = 0; t < TM; ++t) {
                const int issue = wave + t * 4;      // wave-uniform
                const int row = issue * 8 + rl;
                const int gc = pc ^ (row & 7);
                gload_lds16(Ab + (long)row * K + k0 + gc * 8, &As[issue * 512]);
            }
#pragma unroll
            for (int t = 0; t < 4; ++t) {
                const int issue = wave + t * 4;
                const int row = issue * 8 + rl;
                const int gc = pc ^ (row & 7);
                gload_lds16(Bb + (long)row * K + k0 + gc * 8, &Bs[issue * 512]);
            }
            __syncthreads();
            compute_tile(As, Bs, acc, wm, wn, q, rA);
            __syncthreads();
        }
    }

    // epilogue: C/D layout col=lane&15, row=quad*4+reg
    const int rowb = bx * BM + wm + q * 4;
    const int colb = by * 128 + wn + rA;

    if (MODE == 0 && by >= 12) {
        // V segment -> write transposed (Vt[b][o][s]) via LDS tile [128 o][72 pad]
        u16* T = smem;
        __syncthreads();
#pragma unroll
        for (int mi = 0; mi < TM; ++mi)
#pragma unroll
            for (int ni = 0; ni < 4; ++ni) {
                const int lc = wn + ni * 16 + rA;
#pragma unroll
                for (int r = 0; r < 4; ++r) {
                    const int lr = wm + mi * 16 + q * 4 + r;
                    T[lc * 72 + lr] = f2bf(acc[mi][ni][r]);
                }
            }
        __syncthreads();
        const int b = bx >> 5;
        const int s0 = (bx & 31) * 64;
        const int o0 = (by - 12) * 128;
        const int ol = tid >> 1, h = (tid & 1) * 32;
        u16* dst = vt + ((long)b * 768 + o0 + ol) * 2048 + s0 + h;
        const u16* src = &T[ol * 72 + h];
#pragma unroll
        for (int j = 0; j < 4; ++j)
            *(uint4*)(dst + j * 8) = *(const uint4*)(src + j * 8);
        return;
    }

#pragma unroll
    for (int mi = 0; mi < TM; ++mi) {
        if (MODE == 0) {
            const int seg = by / 6;           // 0=Q, 1=K (block-uniform)
            const int ocol = colb - seg * 768;
#pragma unroll
            for (int ni = 0; ni < 4; ++ni)
#pragma unroll
                for (int r = 0; r < 4; ++r)
                    o16[(long)seg * 6291456 + (long)(rowb + mi * 16 + r) * 768 +
                        ocol + ni * 16] = f2bf(acc[mi][ni][r]);
        } else if (MODE == 1) {
            u16* dst = o16 + (long)bz * sO;
            float rs[4] = {0.f, 0.f, 0.f, 0.f};
#pragma unroll
            for (int ni = 0; ni < 4; ++ni)
#pragma unroll
                for (int r = 0; r < 4; ++r) {
                    const float p = __expf(acc[mi][ni][r] * scale);
                    const u16 pb = f2bf(p);
                    dst[(long)(rowb + mi * 16 + r) * ldc + colb + ni * 16] = pb;
                    rs[r] += bf2f(pb);
                }
#pragma unroll
            for (int r = 0; r < 4; ++r) {
#pragma unroll
                for (int off = 1; off <= 8; off <<= 1) rs[r] += __shfl_xor(rs[r], off);
                if (rA == 0)
                    atomicAdd(&rsum[bz * 2048 + rowb + mi * 16 + r], rs[r]);
            }
        } else {
            float* dst = o32 + (long)bz * sO;
            const float4 rs4 = *(const float4*)&rsum[bz * 2048 + rowb + mi * 16];
            const float inv[4] = {1.f / rs4.x, 1.f / rs4.y, 1.f / rs4.z, 1.f / rs4.w};
#pragma unroll
            for (int ni = 0; ni < 4; ++ni)
#pragma unroll
                for (int r = 0; r < 4; ++r)
                    dst[(long)(rowb + mi * 16 + r) * ldc + colb + ni * 16] =
                        acc[mi][ni][r] * inv[r];
        }
    }
}

extern "C" void kernel_launch(void* const* d_in, const int* in_sizes, int n_in,
                              void* d_out, int out_size, void* d_ws, size_t ws_size,
                              hipStream_t stream) {
    const float* x = (const float*)d_in[0];     // [4,2048,768]
    const float* w = (const float*)d_in[1];     // [3,768,768]
    float* out = (float*)d_out;                 // [4,2048,768]

    const long NX = 6291456L;   // 4*2048*768
    const long NS = 16777216L;  // 4*2048*2048

    // layout: [Sb: NS][Qb: NX][Kb: NX][Vt: NX][rowsum: 8192 f32]
    // wt overlays the Sb region (dead before GEMM2 writes Sb)
    u16* Sb = (u16*)d_ws;
    u16* wt = Sb;                 // 1769472 u16 (< NS)
    u16* Qb = Sb + NS;
    u16* Kb = Qb + NX;
    u16* Vt = Kb + NX;
    float* rowsum = (float*)(Vt + NX);

    // 1. W -> Wt[2304][768] bf16 transposed; rowsum <- 0  (x cvt fused into QKV)
    cvt_in_kernel<<<1729, 256, 0, stream>>>(w, wt, rowsum);
    // 2. QKV from raw x fp32: [8192,768] x [2304,768]^T; Q,K direct; V -> Vt
    gemm_bt_kernel<0><<<2304, 256, 0, stream>>>(
        nullptr, x, wt, Qb, nullptr, Vt, nullptr, 768, 0L, 0L, 0L, 768, 1.0f,
        18, 2304);
    // 3. P~ = exp(QK^T/sqrt(300)) bf16 -> Sb, + rowsum atomics
    gemm_bt_kernel<1><<<2048, 256, 0, stream>>>(
        Qb, nullptr, Kb, Sb, nullptr, nullptr, rowsum, 768, 2048L * 768,
        2048L * 768, 2048L * 2048, 2048, 0.057735026918962574f, 16, 512);
    // 4. out = (P~ x Vt^T) / rowsum -> fp32
    gemm_bt_kernel<2><<<768, 256, 0, stream>>>(
        Sb, nullptr, Vt, nullptr, out, nullptr, rowsum, 2048, 2048L * 2048,
        768L * 2048, 2048L * 768, 768, 1.0f, 6, 192);
}

// Round 5
// 196.177 us; speedup vs baseline: 1.0426x; 1.0426x over previous
//
#include <hip/hip_runtime.h>

typedef unsigned short u16;
typedef __attribute__((ext_vector_type(8))) short bf16x8;
typedef __attribute__((ext_vector_type(4))) float f32x4;

#define BK 64
#define TM 2
#define BM 64

__device__ __forceinline__ u16 f2bf(float f) {
    unsigned u = __float_as_uint(f);
    unsigned r = u + 0x7fffu + ((u >> 16) & 1u);
    return (u16)(r >> 16);
}
__device__ __forceinline__ float bf2f(u16 h) {
    return __uint_as_float(((unsigned)h) << 16);
}

__device__ __forceinline__ void gload_lds16(const u16* g, u16* l) {
    __builtin_amdgcn_global_load_lds(
        (__attribute__((address_space(1))) unsigned int*)(u16*)g,
        (__attribute__((address_space(3))) unsigned int*)l,
        16, 0, 0);
}

// ---------- fused input conversion + rowsum zeroing ----------
// blocks [0,6144): x fp32 -> bf16 (float4/thread)
// blocks [6144,7872): kernel[3][768][768] fp32 -> Wt[j*768+o][d] bf16 (transpose)
// block 7872: zero rowsum[8192]
__global__ __launch_bounds__(256) void cvt_in_kernel(const float* __restrict__ x,
                                                     const float* __restrict__ W,
                                                     u16* __restrict__ xb,
                                                     u16* __restrict__ Wt,
                                                     float* __restrict__ rsum) {
    const int bid = blockIdx.x;
    const int tid = threadIdx.x;
    if (bid < 6144) {
        int i = bid * 256 + tid;
        float4 f = ((const float4*)x)[i];
        ushort4 u;
        u.x = f2bf(f.x); u.y = f2bf(f.y); u.z = f2bf(f.z); u.w = f2bf(f.w);
        ((ushort4*)xb)[i] = u;
    } else if (bid < 7872) {
        __shared__ float t[32][33];
        const int b = bid - 6144;
        const int j = b / 576;
        const int rem = b - j * 576;
        const int d0 = (rem % 24) * 32, o0 = (rem / 24) * 32;
        const int tx = tid & 31, ty = tid >> 5;
#pragma unroll
        for (int i = 0; i < 4; i++) {
            int d = d0 + ty + i * 8;
            t[ty + i * 8][tx] = W[((long)j * 768 + d) * 768 + o0 + tx];
        }
        __syncthreads();
#pragma unroll
        for (int i = 0; i < 4; i++) {
            int o = o0 + ty + i * 8;
            Wt[((long)j * 768 + o) * 768 + d0 + tx] = f2bf(t[tx][ty + i * 8]);
        }
    } else {
        const float4 z4 = {0.f, 0.f, 0.f, 0.f};
#pragma unroll
        for (int j = 0; j < 8; j++) ((float4*)rsum)[tid * 8 + j] = z4;
    }
}

// ---------- GEMM: C = A(MxK) * Bt(NxK)^T, bf16 in, fp32 acc ----------
// Round-0-verified structure: 64x128 tile, SINGLE-buffer 24KB LDS, gload_lds
// staging, 2 barriers/K-step. (Measured null/negative here: explicit dbuf,
// TM=4, fp32 reg-staged A.) Plus the one proven win: bijective XCD-chunked
// swizzle (QKV FETCH 56.5->40MB in round 3).
// MODE 0: QKV. by<12 -> Q/K bf16 direct; by>=12 -> V written TRANSPOSED via LDS.
// MODE 1: P~ = exp(s*scale) bf16 + per-row atomic sum into rsum.
// MODE 2: out = acc / rsum[row] -> fp32.
template <int MODE>
__global__ __launch_bounds__(256)
void gemm_bt_kernel(const u16* __restrict__ A, const u16* __restrict__ Bt,
                    u16* __restrict__ o16, float* __restrict__ o32,
                    u16* __restrict__ vt, float* __restrict__ rsum,
                    int K, long sA, long sB, long sO, int ldc, float scale,
                    int ny, int nxy) {
    __shared__ __align__(16) u16 smem[BM * BK + 128 * BK];   // 24576 B
    u16* As = smem;
    u16* Bs = smem + BM * BK;

    // bijective XCD-chunked swizzle: each XCD owns a contiguous task range,
    // by-inner so the B panel stays L2-resident per XCD and consecutive
    // blocks reuse the same A panel.
    const int nb = gridDim.x;            // divisible by 8
    const int chunk = nb >> 3;
    const int nl = (blockIdx.x & 7) * chunk + (blockIdx.x >> 3);
    const int bz = nl / nxy;
    const int rem = nl - bz * nxy;
    const int bx = rem / ny;
    const int by = rem - bx * ny;

    const int tid = threadIdx.x;
    const int lane = tid & 63;
    const int wave = tid >> 6;

    const u16* Ab = A + (long)bz * sA + (long)bx * BM * K;
    const u16* Bb = Bt + (long)bz * sB + (long)by * 128 * K;

    const int rl = lane >> 3;   // row within 8-row staging group
    const int pc = lane & 7;    // 16B chunk position within row
    const int q = lane >> 4;    // quad
    const int rA = lane & 15;
    const int wm = (wave >> 1) * (TM * 16);
    const int wn = (wave & 1) * 64;

    f32x4 acc[TM][4];
    const f32x4 zero = {0.f, 0.f, 0.f, 0.f};
#pragma unroll
    for (int i = 0; i < TM; i++)
#pragma unroll
        for (int j = 0; j < 4; j++) acc[i][j] = zero;

    for (int k0 = 0; k0 < K; k0 += BK) {
        // XOR swizzle: LDS row r position p holds global chunk p^(r&7)
#pragma unroll
        for (int t = 0; t < TM; ++t) {
            const int issue = wave + t * 4;      // wave-uniform
            const int row = issue * 8 + rl;
            const int gc = pc ^ (row & 7);
            gload_lds16(Ab + (long)row * K + k0 + gc * 8, &As[issue * 512]);
        }
#pragma unroll
        for (int t = 0; t < 4; ++t) {
            const int issue = wave + t * 4;
            const int row = issue * 8 + rl;
            const int gc = pc ^ (row & 7);
            gload_lds16(Bb + (long)row * K + k0 + gc * 8, &Bs[issue * 512]);
        }
        __syncthreads();
#pragma unroll
        for (int kk = 0; kk < BK; kk += 32) {
            const int gchunk = (kk >> 3) + q;
            bf16x8 af[TM], bfr[4];
#pragma unroll
            for (int mi = 0; mi < TM; ++mi) {
                const int R = wm + mi * 16 + rA;
                af[mi] = *(const bf16x8*)&As[R * 64 + ((gchunk ^ (R & 7)) << 3)];
            }
#pragma unroll
            for (int ni = 0; ni < 4; ++ni) {
                const int R = wn + ni * 16 + rA;
                bfr[ni] = *(const bf16x8*)&Bs[R * 64 + ((gchunk ^ (R & 7)) << 3)];
            }
#pragma unroll
            for (int mi = 0; mi < TM; ++mi)
#pragma unroll
                for (int ni = 0; ni < 4; ++ni)
                    acc[mi][ni] = __builtin_amdgcn_mfma_f32_16x16x32_bf16(
                        af[mi], bfr[ni], acc[mi][ni], 0, 0, 0);
        }
        __syncthreads();
    }

    // epilogue: C/D layout col=lane&15, row=quad*4+reg
    const int rowb = bx * BM + wm + q * 4;
    const int colb = by * 128 + wn + rA;

    if (MODE == 0 && by >= 12) {
        // V segment -> write transposed (Vt[b][o][s]) via LDS tile [128 o][72 pad]
        u16* T = smem;
#pragma unroll
        for (int mi = 0; mi < TM; ++mi)
#pragma unroll
            for (int ni = 0; ni < 4; ++ni) {
                const int lc = wn + ni * 16 + rA;
#pragma unroll
                for (int r = 0; r < 4; ++r) {
                    const int lr = wm + mi * 16 + q * 4 + r;
                    T[lc * 72 + lr] = f2bf(acc[mi][ni][r]);
                }
            }
        __syncthreads();
        const int b = bx >> 5;
        const int s0 = (bx & 31) * 64;
        const int o0 = (by - 12) * 128;
        const int ol = tid >> 1, h = (tid & 1) * 32;
        u16* dst = vt + ((long)b * 768 + o0 + ol) * 2048 + s0 + h;
        const u16* src = &T[ol * 72 + h];
#pragma unroll
        for (int j = 0; j < 4; ++j)
            *(uint4*)(dst + j * 8) = *(const uint4*)(src + j * 8);
        return;
    }

#pragma unroll
    for (int mi = 0; mi < TM; ++mi) {
        if (MODE == 0) {
            const int seg = by / 6;           // 0=Q, 1=K (block-uniform)
            const int ocol = colb - seg * 768;
#pragma unroll
            for (int ni = 0; ni < 4; ++ni)
#pragma unroll
                for (int r = 0; r < 4; ++r)
                    o16[(long)seg * 6291456 + (long)(rowb + mi * 16 + r) * 768 +
                        ocol + ni * 16] = f2bf(acc[mi][ni][r]);
        } else if (MODE == 1) {
            u16* dst = o16 + (long)bz * sO;
            float rs[4] = {0.f, 0.f, 0.f, 0.f};
#pragma unroll
            for (int ni = 0; ni < 4; ++ni)
#pragma unroll
                for (int r = 0; r < 4; ++r) {
                    const float p = __expf(acc[mi][ni][r] * scale);
                    const u16 pb = f2bf(p);
                    dst[(long)(rowb + mi * 16 + r) * ldc + colb + ni * 16] = pb;
                    rs[r] += bf2f(pb);
                }
#pragma unroll
            for (int r = 0; r < 4; ++r) {
#pragma unroll
                for (int off = 1; off <= 8; off <<= 1) rs[r] += __shfl_xor(rs[r], off);
                if (rA == 0)
                    atomicAdd(&rsum[bz * 2048 + rowb + mi * 16 + r], rs[r]);
            }
        } else {
            float* dst = o32 + (long)bz * sO;
            const float4 rs4 = *(const float4*)&rsum[bz * 2048 + rowb + mi * 16];
            const float inv[4] = {1.f / rs4.x, 1.f / rs4.y, 1.f / rs4.z, 1.f / rs4.w};
#pragma unroll
            for (int ni = 0; ni < 4; ++ni)
#pragma unroll
                for (int r = 0; r < 4; ++r)
                    dst[(long)(rowb + mi * 16 + r) * ldc + colb + ni * 16] =
                        acc[mi][ni][r] * inv[r];
        }
    }
}

extern "C" void kernel_launch(void* const* d_in, const int* in_sizes, int n_in,
                              void* d_out, int out_size, void* d_ws, size_t ws_size,
                              hipStream_t stream) {
    const float* x = (const float*)d_in[0];     // [4,2048,768]
    const float* w = (const float*)d_in[1];     // [3,768,768]
    float* out = (float*)d_out;                 // [4,2048,768]

    const long NX = 6291456L;   // 4*2048*768
    const long NS = 16777216L;  // 4*2048*2048

    // layout: [Sb: NS][Qb: NX][Kb: NX][Vt: NX][rowsum: 8192 f32]  (~71.3 MB)
    // xb+wt overlay the Sb region (dead before GEMM2 writes Sb)
    u16* Sb = (u16*)d_ws;
    u16* xb = Sb;                 // NX
    u16* wt = Sb + NX;            // 1769472  (< NS)
    u16* Qb = Sb + NS;
    u16* Kb = Qb + NX;
    u16* Vt = Kb + NX;
    float* rowsum = (float*)(Vt + NX);

    // 1. x -> bf16; W -> Wt[2304][768] bf16 transposed; rowsum <- 0
    cvt_in_kernel<<<7873, 256, 0, stream>>>(x, w, xb, wt, rowsum);
    // 2. QKV: [8192,768] x [2304,768]^T; Q,K direct; V transposed into Vt
    //    tasks = 128 x 18 (by-inner after swizzle)
    gemm_bt_kernel<0><<<2304, 256, 0, stream>>>(
        xb, wt, Qb, nullptr, Vt, nullptr, 768, 0L, 0L, 0L, 768, 1.0f, 18, 2304);
    // 3. P~ = exp(QK^T/sqrt(300)) bf16 -> Sb, + rowsum atomics
    //    tasks = 32 x 16 x 4
    gemm_bt_kernel<1><<<2048, 256, 0, stream>>>(
        Qb, Kb, Sb, nullptr, nullptr, rowsum, 768, 2048L * 768, 2048L * 768,
        2048L * 2048, 2048, 0.057735026918962574f, 16, 512);
    // 4. out = (P~ x Vt^T) / rowsum -> fp32;  tasks = 32 x 6 x 4
    gemm_bt_kernel<2><<<768, 256, 0, stream>>>(
        Sb, Vt, nullptr, out, nullptr, rowsum, 2048, 2048L * 2048, 768L * 2048,
        2048L * 768, 768, 1.0f, 6, 192);
}

// Round 6
// 190.139 us; speedup vs baseline: 1.0757x; 1.0318x over previous
//
#include <hip/hip_runtime.h>

typedef unsigned short u16;
typedef __attribute__((ext_vector_type(8))) short bf16x8;
typedef __attribute__((ext_vector_type(4))) float f32x4;

#define BK 64
#define TM 2
#define BM 64

__device__ __forceinline__ u16 f2bf(float f) {
    unsigned u = __float_as_uint(f);
    unsigned r = u + 0x7fffu + ((u >> 16) & 1u);
    return (u16)(r >> 16);
}
__device__ __forceinline__ float bf2f(u16 h) {
    return __uint_as_float(((unsigned)h) << 16);
}

__device__ __forceinline__ void gload_lds16(const u16* g, u16* l) {
    __builtin_amdgcn_global_load_lds(
        (__attribute__((address_space(1))) unsigned int*)(u16*)g,
        (__attribute__((address_space(3))) unsigned int*)l,
        16, 0, 0);
}

// ---------- fused input conversion + rowsum zeroing ----------
__global__ __launch_bounds__(256) void cvt_in_kernel(const float* __restrict__ x,
                                                     const float* __restrict__ W,
                                                     u16* __restrict__ xb,
                                                     u16* __restrict__ Wt,
                                                     float* __restrict__ rsum) {
    const int bid = blockIdx.x;
    const int tid = threadIdx.x;
    if (bid < 6144) {
        int i = bid * 256 + tid;
        float4 f = ((const float4*)x)[i];
        ushort4 u;
        u.x = f2bf(f.x); u.y = f2bf(f.y); u.z = f2bf(f.z); u.w = f2bf(f.w);
        ((ushort4*)xb)[i] = u;
    } else if (bid < 7872) {
        __shared__ float t[32][33];
        const int b = bid - 6144;
        const int j = b / 576;
        const int rem = b - j * 576;
        const int d0 = (rem % 24) * 32, o0 = (rem / 24) * 32;
        const int tx = tid & 31, ty = tid >> 5;
#pragma unroll
        for (int i = 0; i < 4; i++) {
            int d = d0 + ty + i * 8;
            t[ty + i * 8][tx] = W[((long)j * 768 + d) * 768 + o0 + tx];
        }
        __syncthreads();
#pragma unroll
        for (int i = 0; i < 4; i++) {
            int o = o0 + ty + i * 8;
            Wt[((long)j * 768 + o) * 768 + d0 + tx] = f2bf(t[tx][ty + i * 8]);
        }
    } else {
        const float4 z4 = {0.f, 0.f, 0.f, 0.f};
#pragma unroll
        for (int j = 0; j < 8; j++) ((float4*)rsum)[tid * 8 + j] = z4;
    }
}

// ---------- small-tile GEMM (QKV / PV), round-0 structure + XCD swizzle ------
template <int MODE>
__global__ __launch_bounds__(256)
void gemm_bt_kernel(const u16* __restrict__ A, const u16* __restrict__ Bt,
                    u16* __restrict__ o16, float* __restrict__ o32,
                    u16* __restrict__ vt, float* __restrict__ rsum,
                    int K, long sA, long sB, long sO, int ldc, float scale,
                    int ny, int nxy) {
    __shared__ __align__(16) u16 smem[BM * BK + 128 * BK];   // 24576 B
    u16* As = smem;
    u16* Bs = smem + BM * BK;

    const int nb = gridDim.x;            // divisible by 8
    const int chunk = nb >> 3;
    const int nl = (blockIdx.x & 7) * chunk + (blockIdx.x >> 3);
    const int bz = nl / nxy;
    const int rem = nl - bz * nxy;
    const int bx = rem / ny;
    const int by = rem - bx * ny;

    const int tid = threadIdx.x;
    const int lane = tid & 63;
    const int wave = tid >> 6;

    const u16* Ab = A + (long)bz * sA + (long)bx * BM * K;
    const u16* Bb = Bt + (long)bz * sB + (long)by * 128 * K;

    const int rl = lane >> 3;
    const int pc = lane & 7;
    const int q = lane >> 4;
    const int rA = lane & 15;
    const int wm = (wave >> 1) * (TM * 16);
    const int wn = (wave & 1) * 64;

    f32x4 acc[TM][4];
    const f32x4 zero = {0.f, 0.f, 0.f, 0.f};
#pragma unroll
    for (int i = 0; i < TM; i++)
#pragma unroll
        for (int j = 0; j < 4; j++) acc[i][j] = zero;

    for (int k0 = 0; k0 < K; k0 += BK) {
#pragma unroll
        for (int t = 0; t < TM; ++t) {
            const int issue = wave + t * 4;
            const int row = issue * 8 + rl;
            const int gc = pc ^ (row & 7);
            gload_lds16(Ab + (long)row * K + k0 + gc * 8, &As[issue * 512]);
        }
#pragma unroll
        for (int t = 0; t < 4; ++t) {
            const int issue = wave + t * 4;
            const int row = issue * 8 + rl;
            const int gc = pc ^ (row & 7);
            gload_lds16(Bb + (long)row * K + k0 + gc * 8, &Bs[issue * 512]);
        }
        __syncthreads();
#pragma unroll
        for (int kk = 0; kk < BK; kk += 32) {
            const int gchunk = (kk >> 3) + q;
            bf16x8 af[TM], bfr[4];
#pragma unroll
            for (int mi = 0; mi < TM; ++mi) {
                const int R = wm + mi * 16 + rA;
                af[mi] = *(const bf16x8*)&As[R * 64 + ((gchunk ^ (R & 7)) << 3)];
            }
#pragma unroll
            for (int ni = 0; ni < 4; ++ni) {
                const int R = wn + ni * 16 + rA;
                bfr[ni] = *(const bf16x8*)&Bs[R * 64 + ((gchunk ^ (R & 7)) << 3)];
            }
#pragma unroll
            for (int mi = 0; mi < TM; ++mi)
#pragma unroll
                for (int ni = 0; ni < 4; ++ni)
                    acc[mi][ni] = __builtin_amdgcn_mfma_f32_16x16x32_bf16(
                        af[mi], bfr[ni], acc[mi][ni], 0, 0, 0);
        }
        __syncthreads();
    }

    const int rowb = bx * BM + wm + q * 4;
    const int colb = by * 128 + wn + rA;

    if (MODE == 0 && by >= 12) {
        u16* T = smem;
#pragma unroll
        for (int mi = 0; mi < TM; ++mi)
#pragma unroll
            for (int ni = 0; ni < 4; ++ni) {
                const int lc = wn + ni * 16 + rA;
#pragma unroll
                for (int r = 0; r < 4; ++r) {
                    const int lr = wm + mi * 16 + q * 4 + r;
                    T[lc * 72 + lr] = f2bf(acc[mi][ni][r]);
                }
            }
        __syncthreads();
        const int b = bx >> 5;
        const int s0 = (bx & 31) * 64;
        const int o0 = (by - 12) * 128;
        const int ol = tid >> 1, h = (tid & 1) * 32;
        u16* dst = vt + ((long)b * 768 + o0 + ol) * 2048 + s0 + h;
        const u16* src = &T[ol * 72 + h];
#pragma unroll
        for (int j = 0; j < 4; ++j)
            *(uint4*)(dst + j * 8) = *(const uint4*)(src + j * 8);
        return;
    }

#pragma unroll
    for (int mi = 0; mi < TM; ++mi) {
        if (MODE == 0) {
            const int seg = by / 6;
            const int ocol = colb - seg * 768;
#pragma unroll
            for (int ni = 0; ni < 4; ++ni)
#pragma unroll
                for (int r = 0; r < 4; ++r)
                    o16[(long)seg * 6291456 + (long)(rowb + mi * 16 + r) * 768 +
                        ocol + ni * 16] = f2bf(acc[mi][ni][r]);
        } else {
            float* dst = o32 + (long)bz * sO;
            const float4 rs4 = *(const float4*)&rsum[bz * 2048 + rowb + mi * 16];
            const float inv[4] = {1.f / rs4.x, 1.f / rs4.y, 1.f / rs4.z, 1.f / rs4.w};
#pragma unroll
            for (int ni = 0; ni < 4; ++ni)
#pragma unroll
                for (int r = 0; r < 4; ++r)
                    dst[(long)(rowb + mi * 16 + r) * ldc + colb + ni * 16] =
                        acc[mi][ni][r] * inv[r];
        }
    }
}

// ---------- scores: 256x256 tile, 8 waves, counted-vmcnt double-buffer -------
// P~ = exp(QK^T * scale) bf16 -> Sb + per-row atomic rowsum.
// Structure: per K-tile pair {STAGE(b1,t+1); vmcnt(8); bar; MFMA(b0); bar;
// STAGE(b0,t+2); vmcnt(8); bar; MFMA(b1); bar}. Raw s_barrier (NOT
// __syncthreads: that re-inserts the vmcnt(0) drain). vmcnt(8) = keep the
// just-issued tile (8 loads/thread) in flight, force the older tile complete.
// Every overwrite issues only after the barrier that ends that buffer's reads.
__device__ __forceinline__ void sc_stage(const u16* Ab, const u16* Bb, u16* A_,
                                         int t, int w, int rl, int pc) {
    const int k0 = t * 64;
    u16* B_ = A_ + 16384;
#pragma unroll
    for (int j = 0; j < 4; ++j) {
        const int g = w + j * 8;              // wave-uniform, 0..31
        const int row = g * 8 + rl;
        const int gc = pc ^ (row & 7);
        gload_lds16(Ab + (long)row * 768 + k0 + gc * 8, &A_[g * 512]);
    }
#pragma unroll
    for (int j = 0; j < 4; ++j) {
        const int g = w + j * 8;
        const int row = g * 8 + rl;
        const int gc = pc ^ (row & 7);
        gload_lds16(Bb + (long)row * 768 + k0 + gc * 8, &B_[g * 512]);
    }
}

__device__ __forceinline__ void sc_comp(const u16* A_, f32x4 (&acc)[8][4],
                                        int wm, int wn, int q, int rA) {
    const u16* B_ = A_ + 16384;
    __builtin_amdgcn_s_setprio(1);
#pragma unroll
    for (int kk = 0; kk < 64; kk += 32) {
        const int gchunk = (kk >> 3) + q;
        bf16x8 bfr[4];
#pragma unroll
        for (int ni = 0; ni < 4; ++ni) {
            const int R = wn + ni * 16 + rA;
            bfr[ni] = *(const bf16x8*)&B_[R * 64 + ((gchunk ^ (R & 7)) << 3)];
        }
#pragma unroll
        for (int mi = 0; mi < 8; ++mi) {
            const int R = wm + mi * 16 + rA;
            const bf16x8 af = *(const bf16x8*)&A_[R * 64 + ((gchunk ^ (R & 7)) << 3)];
#pragma unroll
            for (int ni = 0; ni < 4; ++ni)
                acc[mi][ni] = __builtin_amdgcn_mfma_f32_16x16x32_bf16(
                    af, bfr[ni], acc[mi][ni], 0, 0, 0);
        }
    }
    __builtin_amdgcn_s_setprio(0);
}

__global__ __launch_bounds__(512, 2)
void scores256_kernel(const u16* __restrict__ Q, const u16* __restrict__ Kb,
                      u16* __restrict__ Sb, float* __restrict__ rsum) {
    __shared__ __align__(16) u16 smem[65536];   // [As0|Bs0|As1|Bs1] = 128 KiB

    const int nb = gridDim.x;                   // 256
    const int chunk = nb >> 3;
    const int nl = (blockIdx.x & 7) * chunk + (blockIdx.x >> 3);
    const int bz = nl >> 6;
    const int rem = nl & 63;
    const int bx = rem >> 3;
    const int by = rem & 7;

    const int tid = threadIdx.x;
    const int lane = tid & 63;
    const int w = tid >> 6;

    const u16* Ab = Q + (long)bz * 1572864L + (long)bx * 256 * 768;
    const u16* Bb = Kb + (long)bz * 1572864L + (long)by * 256 * 768;

    const int rl = lane >> 3, pc = lane & 7;
    const int q = lane >> 4, rA = lane & 15;
    const int wm = (w >> 2) * 128, wn = (w & 3) * 64;

    f32x4 acc[8][4];
    const f32x4 zero = {0.f, 0.f, 0.f, 0.f};
#pragma unroll
    for (int i = 0; i < 8; i++)
#pragma unroll
        for (int j = 0; j < 4; j++) acc[i][j] = zero;

    u16* buf0 = smem;
    u16* buf1 = smem + 32768;

    sc_stage(Ab, Bb, buf0, 0, w, rl, pc);       // prologue: tile 0 -> buf0
    for (int i = 0; i < 6; ++i) {               // NT = 768/64 = 12, 2 tiles/iter
        sc_stage(Ab, Bb, buf1, 2 * i + 1, w, rl, pc);
        asm volatile("s_waitcnt vmcnt(8)" ::: "memory");   // force buf0 tile done
        __builtin_amdgcn_sched_barrier(0);
        __builtin_amdgcn_s_barrier();
        sc_comp(buf0, acc, wm, wn, q, rA);
        __builtin_amdgcn_s_barrier();           // all waves done reading buf0
        if (2 * i + 2 < 12) {
            sc_stage(Ab, Bb, buf0, 2 * i + 2, w, rl, pc);
            asm volatile("s_waitcnt vmcnt(8)" ::: "memory"); // force buf1 done
        } else {
            asm volatile("s_waitcnt vmcnt(0)" ::: "memory");
        }
        __builtin_amdgcn_sched_barrier(0);
        __builtin_amdgcn_s_barrier();
        sc_comp(buf1, acc, wm, wn, q, rA);
        __builtin_amdgcn_s_barrier();           // all waves done reading buf1
    }

    // epilogue: exp + bf16 store + rowsum atomics
    const int rowb = bx * 256 + wm + q * 4;
    const int colb = by * 256 + wn + rA;
    u16* dst = Sb + (long)bz * 4194304L;
    const float scale = 0.057735026918962574f;
#pragma unroll
    for (int mi = 0; mi < 8; ++mi) {
        float rs[4] = {0.f, 0.f, 0.f, 0.f};
#pragma unroll
        for (int ni = 0; ni < 4; ++ni)
#pragma unroll
            for (int r = 0; r < 4; ++r) {
                const float p = __expf(acc[mi][ni][r] * scale);
                const u16 pb = f2bf(p);
                dst[(long)(rowb + mi * 16 + r) * 2048 + colb + ni * 16] = pb;
                rs[r] += bf2f(pb);
            }
#pragma unroll
        for (int r = 0; r < 4; ++r) {
#pragma unroll
            for (int off = 1; off <= 8; off <<= 1) rs[r] += __shfl_xor(rs[r], off);
            if (rA == 0)
                atomicAdd(&rsum[bz * 2048 + rowb + mi * 16 + r], rs[r]);
        }
    }
}

extern "C" void kernel_launch(void* const* d_in, const int* in_sizes, int n_in,
                              void* d_out, int out_size, void* d_ws, size_t ws_size,
                              hipStream_t stream) {
    const float* x = (const float*)d_in[0];     // [4,2048,768]
    const float* w = (const float*)d_in[1];     // [3,768,768]
    float* out = (float*)d_out;                 // [4,2048,768]

    const long NX = 6291456L;   // 4*2048*768
    const long NS = 16777216L;  // 4*2048*2048

    u16* Sb = (u16*)d_ws;
    u16* xb = Sb;                 // NX (overlay, dead before scores writes Sb)
    u16* wt = Sb + NX;            // 1769472  (< NS)
    u16* Qb = Sb + NS;
    u16* Kb = Qb + NX;
    u16* Vt = Kb + NX;
    float* rowsum = (float*)(Vt + NX);

    // 1. x -> bf16; W -> Wt[2304][768] bf16 transposed; rowsum <- 0
    cvt_in_kernel<<<7873, 256, 0, stream>>>(x, w, xb, wt, rowsum);
    // 2. QKV: [8192,768] x [2304,768]^T; Q,K direct; V transposed into Vt
    gemm_bt_kernel<0><<<2304, 256, 0, stream>>>(
        xb, wt, Qb, nullptr, Vt, nullptr, 768, 0L, 0L, 0L, 768, 1.0f, 18, 2304);
    // 3. P~ = exp(QK^T/sqrt(300)) bf16 -> Sb, + rowsum atomics
    //    256x256 tiles: 8 x 8 x 4 = 256 blocks = 1/CU, counted-vmcnt pipeline
    scores256_kernel<<<256, 512, 0, stream>>>(Qb, Kb, Sb, rowsum);
    // 4. out = (P~ x Vt^T) / rowsum -> fp32;  tasks = 32 x 6 x 4
    gemm_bt_kernel<2><<<768, 256, 0, stream>>>(
        Sb, Vt, nullptr, out, nullptr, rowsum, 2048, 2048L * 2048, 768L * 2048,
        2048L * 768, 768, 1.0f, 6, 192);
}

// Round 7
// 189.781 us; speedup vs baseline: 1.0777x; 1.0019x over previous
//
#include <hip/hip_runtime.h>

typedef unsigned short u16;
typedef __attribute__((ext_vector_type(8))) short bf16x8;
typedef __attribute__((ext_vector_type(4))) float f32x4;

#define BK 64
#define TM 2
#define BM 64

__device__ __forceinline__ u16 f2bf(float f) {
    unsigned u = __float_as_uint(f);
    unsigned r = u + 0x7fffu + ((u >> 16) & 1u);
    return (u16)(r >> 16);
}
__device__ __forceinline__ float bf2f(u16 h) {
    return __uint_as_float(((unsigned)h) << 16);
}

__device__ __forceinline__ void gload_lds16(const u16* g, u16* l) {
    __builtin_amdgcn_global_load_lds(
        (__attribute__((address_space(1))) unsigned int*)(u16*)g,
        (__attribute__((address_space(3))) unsigned int*)l,
        16, 0, 0);
}

// ---------- fused input conversion + rowsum zeroing ----------
__global__ __launch_bounds__(256) void cvt_in_kernel(const float* __restrict__ x,
                                                     const float* __restrict__ W,
                                                     u16* __restrict__ xb,
                                                     u16* __restrict__ Wt,
                                                     float* __restrict__ rsum) {
    const int bid = blockIdx.x;
    const int tid = threadIdx.x;
    if (bid < 6144) {
        int i = bid * 256 + tid;
        float4 f = ((const float4*)x)[i];
        ushort4 u;
        u.x = f2bf(f.x); u.y = f2bf(f.y); u.z = f2bf(f.z); u.w = f2bf(f.w);
        ((ushort4*)xb)[i] = u;
    } else if (bid < 7872) {
        __shared__ float t[32][33];
        const int b = bid - 6144;
        const int j = b / 576;
        const int rem = b - j * 576;
        const int d0 = (rem % 24) * 32, o0 = (rem / 24) * 32;
        const int tx = tid & 31, ty = tid >> 5;
#pragma unroll
        for (int i = 0; i < 4; i++) {
            int d = d0 + ty + i * 8;
            t[ty + i * 8][tx] = W[((long)j * 768 + d) * 768 + o0 + tx];
        }
        __syncthreads();
#pragma unroll
        for (int i = 0; i < 4; i++) {
            int o = o0 + ty + i * 8;
            Wt[((long)j * 768 + o) * 768 + d0 + tx] = f2bf(t[tx][ty + i * 8]);
        }
    } else {
        const float4 z4 = {0.f, 0.f, 0.f, 0.f};
#pragma unroll
        for (int j = 0; j < 8; j++) ((float4*)rsum)[tid * 8 + j] = z4;
    }
}

// stage one (A,B) K-tile into LDS buffer p (A at p, B at p+BM*BK), XOR-swizzled
__device__ __forceinline__ void stage_tiles(const u16* Ab, const u16* Bb, int K,
                                            int k0, u16* p, int wave, int rl,
                                            int pc) {
    u16* As = p;
    u16* Bs = p + BM * BK;
#pragma unroll
    for (int t = 0; t < TM; ++t) {
        const int issue = wave + t * 4;      // wave-uniform
        const int row = issue * 8 + rl;
        const int gc = pc ^ (row & 7);
        gload_lds16(Ab + (long)row * K + k0 + gc * 8, &As[issue * 512]);
    }
#pragma unroll
    for (int t = 0; t < 4; ++t) {
        const int issue = wave + t * 4;
        const int row = issue * 8 + rl;
        const int gc = pc ^ (row & 7);
        gload_lds16(Bb + (long)row * K + k0 + gc * 8, &Bs[issue * 512]);
    }
}

// 16 MFMA on one staged K-tile (XOR-swizzled LDS layout)
__device__ __forceinline__ void compute_tile(const u16* p, f32x4 (&acc)[TM][4],
                                             int wm, int wn, int q, int rA) {
    const u16* As = p;
    const u16* Bs = p + BM * BK;
#pragma unroll
    for (int kk = 0; kk < BK; kk += 32) {
        const int gchunk = (kk >> 3) + q;
        bf16x8 af[TM], bfr[4];
#pragma unroll
        for (int mi = 0; mi < TM; ++mi) {
            const int R = wm + mi * 16 + rA;
            af[mi] = *(const bf16x8*)&As[R * 64 + ((gchunk ^ (R & 7)) << 3)];
        }
#pragma unroll
        for (int ni = 0; ni < 4; ++ni) {
            const int R = wn + ni * 16 + rA;
            bfr[ni] = *(const bf16x8*)&Bs[R * 64 + ((gchunk ^ (R & 7)) << 3)];
        }
#pragma unroll
        for (int mi = 0; mi < TM; ++mi)
#pragma unroll
            for (int ni = 0; ni < 4; ++ni)
                acc[mi][ni] = __builtin_amdgcn_mfma_f32_16x16x32_bf16(
                    af[mi], bfr[ni], acc[mi][ni], 0, 0, 0);
    }
}

// ---------- small-tile GEMM (QKV / PV): 64x128, TRIPLE-buffer counted-vmcnt --
// Mechanism proven by scores256 (round 6): raw s_barrier + counted vmcnt keeps
// staging loads in flight across barriers (__syncthreads would drain vmcnt(0)).
// 3 x 24KB LDS = 72KB -> 2 blocks/CU; 2-tile-deep prefetch; vmcnt(12) = keep
// the 2 newest stages (6 loads each) in flight, force stage t complete.
// MODE 0: QKV. by<12 -> Q/K bf16 direct; by>=12 -> V written TRANSPOSED via LDS.
// MODE 2: out = acc / rsum[row] -> fp32.
template <int MODE>
__global__ __launch_bounds__(256)
void gemm_bt_kernel(const u16* __restrict__ A, const u16* __restrict__ Bt,
                    u16* __restrict__ o16, float* __restrict__ o32,
                    u16* __restrict__ vt, float* __restrict__ rsum,
                    int K, long sA, long sB, long sO, int ldc, float scale,
                    int ny, int nxy) {
    constexpr int BUF = BM * BK + 128 * BK;              // 12288 u16
    __shared__ __align__(16) u16 smem[3 * BUF];          // 73728 B

    const int nb = gridDim.x;            // divisible by 8
    const int chunk = nb >> 3;
    const int nl = (blockIdx.x & 7) * chunk + (blockIdx.x >> 3);
    const int bz = nl / nxy;
    const int rem = nl - bz * nxy;
    const int bx = rem / ny;
    const int by = rem - bx * ny;

    const int tid = threadIdx.x;
    const int lane = tid & 63;
    const int wave = tid >> 6;

    const u16* Ab = A + (long)bz * sA + (long)bx * BM * K;
    const u16* Bb = Bt + (long)bz * sB + (long)by * 128 * K;

    const int rl = lane >> 3;
    const int pc = lane & 7;
    const int q = lane >> 4;
    const int rA = lane & 15;
    const int wm = (wave >> 1) * (TM * 16);
    const int wn = (wave & 1) * 64;

    f32x4 acc[TM][4];
    const f32x4 zero = {0.f, 0.f, 0.f, 0.f};
#pragma unroll
    for (int i = 0; i < TM; i++)
#pragma unroll
        for (int j = 0; j < 4; j++) acc[i][j] = zero;

    u16* p0 = smem;
    u16* p1 = smem + BUF;
    u16* p2 = smem + 2 * BUF;

    const int NT = K >> 6;               // 12 (QKV) or 32 (PV)
    stage_tiles(Ab, Bb, K, 0, p0, wave, rl, pc);
    stage_tiles(Ab, Bb, K, BK, p1, wave, rl, pc);
    for (int t = 0; t < NT; ++t) {
        if (t + 2 < NT) {
            // overwrites the buffer last read at compute(t-1) -- safe: every
            // wave passed the barrier ending iteration t-1 before this issues.
            stage_tiles(Ab, Bb, K, (t + 2) * BK, p2, wave, rl, pc);
            asm volatile("s_waitcnt vmcnt(12)" ::: "memory");   // stage t done
        } else if (t + 1 < NT) {
            asm volatile("s_waitcnt vmcnt(6)" ::: "memory");
        } else {
            asm volatile("s_waitcnt vmcnt(0)" ::: "memory");
        }
        __builtin_amdgcn_sched_barrier(0);
        __builtin_amdgcn_s_barrier();    // all threads' stage-t loads landed
        compute_tile(p0, acc, wm, wn, q, rA);
        __builtin_amdgcn_s_barrier();    // all waves done reading p0
        u16* tmp = p0; p0 = p1; p1 = p2; p2 = tmp;
    }

    // epilogue: C/D layout col=lane&15, row=quad*4+reg
    const int rowb = bx * BM + wm + q * 4;
    const int colb = by * 128 + wn + rA;

    if (MODE == 0 && by >= 12) {
        u16* T = smem;
#pragma unroll
        for (int mi = 0; mi < TM; ++mi)
#pragma unroll
            for (int ni = 0; ni < 4; ++ni) {
                const int lc = wn + ni * 16 + rA;
#pragma unroll
                for (int r = 0; r < 4; ++r) {
                    const int lr = wm + mi * 16 + q * 4 + r;
                    T[lc * 72 + lr] = f2bf(acc[mi][ni][r]);
                }
            }
        __syncthreads();
        const int b = bx >> 5;
        const int s0 = (bx & 31) * 64;
        const int o0 = (by - 12) * 128;
        const int ol = tid >> 1, h = (tid & 1) * 32;
        u16* dst = vt + ((long)b * 768 + o0 + ol) * 2048 + s0 + h;
        const u16* src = &T[ol * 72 + h];
#pragma unroll
        for (int j = 0; j < 4; ++j)
            *(uint4*)(dst + j * 8) = *(const uint4*)(src + j * 8);
        return;
    }

#pragma unroll
    for (int mi = 0; mi < TM; ++mi) {
        if (MODE == 0) {
            const int seg = by / 6;
            const int ocol = colb - seg * 768;
#pragma unroll
            for (int ni = 0; ni < 4; ++ni)
#pragma unroll
                for (int r = 0; r < 4; ++r)
                    o16[(long)seg * 6291456 + (long)(rowb + mi * 16 + r) * 768 +
                        ocol + ni * 16] = f2bf(acc[mi][ni][r]);
        } else {
            float* dst = o32 + (long)bz * sO;
            const float4 rs4 = *(const float4*)&rsum[bz * 2048 + rowb + mi * 16];
            const float inv[4] = {1.f / rs4.x, 1.f / rs4.y, 1.f / rs4.z, 1.f / rs4.w};
#pragma unroll
            for (int ni = 0; ni < 4; ++ni)
#pragma unroll
                for (int r = 0; r < 4; ++r)
                    dst[(long)(rowb + mi * 16 + r) * ldc + colb + ni * 16] =
                        acc[mi][ni][r] * inv[r];
        }
    }
}

// ---------- scores: 256x256 tile, 8 waves, counted-vmcnt double-buffer -------
__device__ __forceinline__ void sc_stage(const u16* Ab, const u16* Bb, u16* A_,
                                         int t, int w, int rl, int pc) {
    const int k0 = t * 64;
    u16* B_ = A_ + 16384;
#pragma unroll
    for (int j = 0; j < 4; ++j) {
        const int g = w + j * 8;              // wave-uniform, 0..31
        const int row = g * 8 + rl;
        const int gc = pc ^ (row & 7);
        gload_lds16(Ab + (long)row * 768 + k0 + gc * 8, &A_[g * 512]);
    }
#pragma unroll
    for (int j = 0; j < 4; ++j) {
        const int g = w + j * 8;
        const int row = g * 8 + rl;
        const int gc = pc ^ (row & 7);
        gload_lds16(Bb + (long)row * 768 + k0 + gc * 8, &B_[g * 512]);
    }
}

__device__ __forceinline__ void sc_comp(const u16* A_, f32x4 (&acc)[8][4],
                                        int wm, int wn, int q, int rA) {
    const u16* B_ = A_ + 16384;
    __builtin_amdgcn_s_setprio(1);
#pragma unroll
    for (int kk = 0; kk < 64; kk += 32) {
        const int gchunk = (kk >> 3) + q;
        bf16x8 bfr[4];
#pragma unroll
        for (int ni = 0; ni < 4; ++ni) {
            const int R = wn + ni * 16 + rA;
            bfr[ni] = *(const bf16x8*)&B_[R * 64 + ((gchunk ^ (R & 7)) << 3)];
        }
#pragma unroll
        for (int mi = 0; mi < 8; ++mi) {
            const int R = wm + mi * 16 + rA;
            const bf16x8 af = *(const bf16x8*)&A_[R * 64 + ((gchunk ^ (R & 7)) << 3)];
#pragma unroll
            for (int ni = 0; ni < 4; ++ni)
                acc[mi][ni] = __builtin_amdgcn_mfma_f32_16x16x32_bf16(
                    af, bfr[ni], acc[mi][ni], 0, 0, 0);
        }
    }
    __builtin_amdgcn_s_setprio(0);
}

__global__ __launch_bounds__(512, 2)
void scores256_kernel(const u16* __restrict__ Q, const u16* __restrict__ Kb,
                      u16* __restrict__ Sb, float* __restrict__ rsum) {
    __shared__ __align__(16) u16 smem[65536];   // [As0|Bs0|As1|Bs1] = 128 KiB

    const int nb = gridDim.x;                   // 256
    const int chunk = nb >> 3;
    const int nl = (blockIdx.x & 7) * chunk + (blockIdx.x >> 3);
    const int bz = nl >> 6;
    const int rem = nl & 63;
    const int bx = rem >> 3;
    const int by = rem & 7;

    const int tid = threadIdx.x;
    const int lane = tid & 63;
    const int w = tid >> 6;

    const u16* Ab = Q + (long)bz * 1572864L + (long)bx * 256 * 768;
    const u16* Bb = Kb + (long)bz * 1572864L + (long)by * 256 * 768;

    const int rl = lane >> 3, pc = lane & 7;
    const int q = lane >> 4, rA = lane & 15;
    const int wm = (w >> 2) * 128, wn = (w & 3) * 64;

    f32x4 acc[8][4];
    const f32x4 zero = {0.f, 0.f, 0.f, 0.f};
#pragma unroll
    for (int i = 0; i < 8; i++)
#pragma unroll
        for (int j = 0; j < 4; j++) acc[i][j] = zero;

    u16* buf0 = smem;
    u16* buf1 = smem + 32768;

    sc_stage(Ab, Bb, buf0, 0, w, rl, pc);       // prologue: tile 0 -> buf0
    for (int i = 0; i < 6; ++i) {               // NT = 768/64 = 12, 2 tiles/iter
        sc_stage(Ab, Bb, buf1, 2 * i + 1, w, rl, pc);
        asm volatile("s_waitcnt vmcnt(8)" ::: "memory");   // force buf0 tile done
        __builtin_amdgcn_sched_barrier(0);
        __builtin_amdgcn_s_barrier();
        sc_comp(buf0, acc, wm, wn, q, rA);
        __builtin_amdgcn_s_barrier();           // all waves done reading buf0
        if (2 * i + 2 < 12) {
            sc_stage(Ab, Bb, buf0, 2 * i + 2, w, rl, pc);
            asm volatile("s_waitcnt vmcnt(8)" ::: "memory"); // force buf1 done
        } else {
            asm volatile("s_waitcnt vmcnt(0)" ::: "memory");
        }
        __builtin_amdgcn_sched_barrier(0);
        __builtin_amdgcn_s_barrier();
        sc_comp(buf1, acc, wm, wn, q, rA);
        __builtin_amdgcn_s_barrier();           // all waves done reading buf1
    }

    // epilogue: exp + bf16 store + rowsum atomics
    const int rowb = bx * 256 + wm + q * 4;
    const int colb = by * 256 + wn + rA;
    u16* dst = Sb + (long)bz * 4194304L;
    const float scale = 0.057735026918962574f;
#pragma unroll
    for (int mi = 0; mi < 8; ++mi) {
        float rs[4] = {0.f, 0.f, 0.f, 0.f};
#pragma unroll
        for (int ni = 0; ni < 4; ++ni)
#pragma unroll
            for (int r = 0; r < 4; ++r) {
                const float p = __expf(acc[mi][ni][r] * scale);
                const u16 pb = f2bf(p);
                dst[(long)(rowb + mi * 16 + r) * 2048 + colb + ni * 16] = pb;
                rs[r] += bf2f(pb);
            }
#pragma unroll
        for (int r = 0; r < 4; ++r) {
#pragma unroll
            for (int off = 1; off <= 8; off <<= 1) rs[r] += __shfl_xor(rs[r], off);
            if (rA == 0)
                atomicAdd(&rsum[bz * 2048 + rowb + mi * 16 + r], rs[r]);
        }
    }
}

extern "C" void kernel_launch(void* const* d_in, const int* in_sizes, int n_in,
                              void* d_out, int out_size, void* d_ws, size_t ws_size,
                              hipStream_t stream) {
    const float* x = (const float*)d_in[0];     // [4,2048,768]
    const float* w = (const float*)d_in[1];     // [3,768,768]
    float* out = (float*)d_out;                 // [4,2048,768]

    const long NX = 6291456L;   // 4*2048*768
    const long NS = 16777216L;  // 4*2048*2048

    u16* Sb = (u16*)d_ws;
    u16* xb = Sb;                 // NX (overlay, dead before scores writes Sb)
    u16* wt = Sb + NX;            // 1769472  (< NS)
    u16* Qb = Sb + NS;
    u16* Kb = Qb + NX;
    u16* Vt = Kb + NX;
    float* rowsum = (float*)(Vt + NX);

    // 1. x -> bf16; W -> Wt[2304][768] bf16 transposed; rowsum <- 0
    cvt_in_kernel<<<7873, 256, 0, stream>>>(x, w, xb, wt, rowsum);
    // 2. QKV: [8192,768] x [2304,768]^T; Q,K direct; V transposed into Vt
    gemm_bt_kernel<0><<<2304, 256, 0, stream>>>(
        xb, wt, Qb, nullptr, Vt, nullptr, 768, 0L, 0L, 0L, 768, 1.0f, 18, 2304);
    // 3. P~ = exp(QK^T/sqrt(300)) bf16 -> Sb, + rowsum atomics
    //    256x256 tiles: 8 x 8 x 4 = 256 blocks = 1/CU, counted-vmcnt pipeline
    scores256_kernel<<<256, 512, 0, stream>>>(Qb, Kb, Sb, rowsum);
    // 4. out = (P~ x Vt^T) / rowsum -> fp32;  tasks = 32 x 6 x 4
    gemm_bt_kernel<2><<<768, 256, 0, stream>>>(
        Sb, Vt, nullptr, out, nullptr, rowsum, 2048, 2048L * 2048, 768L * 2048,
        2048L * 768, 768, 1.0f, 6, 192);
}